// Round 13
// baseline (599.917 us; speedup 1.0000x reference)
//
#include <hip/hip_runtime.h>
#include <hip/hip_fp16.h>

#define HH 8
#define FIN 64
#define CHUNK 8192       // edges per partA block
#define NPB 1024         // dst nodes per bucket
#define NPB_SHIFT 10
#define MAXNB 256        // max buckets (N <= 262144; also r must fit 18 bits)
#define SUBCH 8192       // records per partB pass (45KB LDS -> 3 blocks/CU)
#define RSH 18           // record: (local_c << RSH) | r
#define RMASK 0x3FFFFu

// ---------- helpers ----------
__device__ __forceinline__ float b2f(unsigned short u) {
  union { unsigned int i; float f; } x;
  x.i = ((unsigned int)u) << 16;
  return x.f;
}

__device__ __forceinline__ float lrelu(float x) { return x > 0.f ? x : 0.2f * x; }

__device__ __forceinline__ float ld(const void* p, int i, int isf) {
  return isf ? ((const float*)p)[i] : b2f(((const unsigned short*)p)[i]);
}

// fast tanh via __expf (clamped; |err| ~1e-7 in the used range)
__device__ __forceinline__ float tanhf_fast(float x) {
  float xc = fminf(fmaxf(x, -15.f), 15.f);
  float e = __expf(2.f * xc);
  return 1.f - 2.f / (e + 1.f);
}

// per-metapath argument bundle
struct MP {
  const int* ei;
  const float* ad;      // dst attention dot (coalesced, hoisted per node)
  const float* pk;      // packed rows: [n*8] = {h[8] fp16 (16B), as fp32, pad} 32B
  float* den;
  float* out;
  unsigned* sorted;     // 4-B records, bucket b at [b*rcap, ...)
  int* gcur;            // per-bucket allocation cursors (256 ints)
  int E;
  int nchunks;
  int rcap;
};
struct MP4 { MP m[4]; };

// projection bundle (3 node types in one launch)
// dA -> packed row pkA; dB -> pkB (nullable); dC/dD -> plain arrays (nullable)
struct PJ {
  const void* x; const void* W; const void* b;
  const void* aA; float* pkA;
  const void* aB; float* pkB;
  const void* aC; float* sC;
  const void* aD; float* sD;
};
struct PJ3 { PJ p[3]; };

// score/pred bundles (2 groups in one launch)
struct SC { const float *o0, *d0, *o1, *d1; float* score; };
struct SC2 { SC g[2]; };
struct PR { const float *o0, *d0, *o1, *d1; const float* score;
            const void* linW; const void* linb; float* outp; };
struct PR2 { PR g[2]; };

// ---------- setup: dtype detect + zero score + init cursors (one launch) ----------
__global__ void __launch_bounds__(1024)
setup_kernel(const unsigned short* __restrict__ x, int* __restrict__ flag,
             float* __restrict__ score_all, int* __restrict__ gcur, int rcap) {
  __shared__ int tot;
  int t = threadIdx.x;
  gcur[t] = (t & 255) * rcap;
  if (t < 4) score_all[t] = 0.f;
  if (t == 0) tot = 0;
  __syncthreads();
  int cnt = 0;
  for (int i = t; i < 2048; i += 1024) {
    int e = (x[i] >> 7) & 0xFF;
    if (e >= 0x90) cnt++;
  }
  if (cnt) atomicAdd(&tot, cnt);
  __syncthreads();
  if (t == 0) flag[0] = (tot >= 8) ? 1 : 0;
}

// ---------- projection: packed rows {h fp16, as fp32} + plain ad dots ----------
__global__ void __launch_bounds__(256)
proj_kernel(PJ3 pj, int N, const int* __restrict__ flag) {
  const PJ P = pj.p[blockIdx.y];
  __shared__ float Wl[FIN][HH];
  __shared__ float bl[HH];
  __shared__ float al[4][HH];
  int isf = flag[0];
  int t = threadIdx.x;
  for (int i = t; i < FIN * HH; i += blockDim.x) Wl[i >> 3][i & 7] = ld(P.W, i, isf);
  if (t < HH) {
    bl[t] = ld(P.b, t, isf);
    al[0][t] = P.aA ? ld(P.aA, t, isf) : 0.f;
    al[1][t] = P.aB ? ld(P.aB, t, isf) : 0.f;
    al[2][t] = P.aC ? ld(P.aC, t, isf) : 0.f;
    al[3][t] = P.aD ? ld(P.aD, t, isf) : 0.f;
  }
  __syncthreads();
  int n = blockIdx.x * blockDim.x + t;
  if (n >= N) return;
  float acc[HH];
#pragma unroll
  for (int j = 0; j < HH; ++j) acc[j] = bl[j];
  if (isf) {
    const float4* xr = (const float4*)((const float*)P.x + (size_t)n * FIN);
#pragma unroll
    for (int v = 0; v < FIN / 4; ++v) {
      float4 p = xr[v];
      float f4[4] = {p.x, p.y, p.z, p.w};
#pragma unroll
      for (int k = 0; k < 4; ++k) {
        int f = v * 4 + k;
#pragma unroll
        for (int j = 0; j < HH; ++j) acc[j] += f4[k] * Wl[f][j];
      }
    }
  } else {
    const uint4* xr = (const uint4*)((const unsigned short*)P.x + (size_t)n * FIN);
#pragma unroll
    for (int v = 0; v < FIN / 8; ++v) {
      uint4 p = xr[v];
      unsigned int w[4] = {p.x, p.y, p.z, p.w};
#pragma unroll
      for (int k = 0; k < 4; ++k) {
        float f0 = __uint_as_float(w[k] << 16);
        float f1 = __uint_as_float(w[k] & 0xFFFF0000u);
        int f = v * 8 + k * 2;
#pragma unroll
        for (int j = 0; j < HH; ++j) acc[j] += f0 * Wl[f][j];
#pragma unroll
        for (int j = 0; j < HH; ++j) acc[j] += f1 * Wl[f + 1][j];
      }
    }
  }
  union { __half h[8]; uint4 u; } pkh;
#pragma unroll
  for (int j = 0; j < HH; ++j) pkh.h[j] = __float2half(acc[j]);
  float dA = 0.f, dB = 0.f, dC = 0.f, dD = 0.f;
#pragma unroll
  for (int j = 0; j < HH; ++j) {
    dA += acc[j] * al[0][j];
    dB += acc[j] * al[1][j];
    dC += acc[j] * al[2][j];
    dD += acc[j] * al[3][j];
  }
  if (P.pkA) {
    float* rp = P.pkA + (size_t)n * 8;
    *(uint4*)rp = pkh.u;
    rp[4] = dA;
  }
  if (P.pkB) {
    float* rp = P.pkB + (size_t)n * 8;
    *(uint4*)rp = pkh.u;
    rp[4] = dB;
  }
  if (P.sC) P.sC[n] = dC;
  if (P.sD) P.sD[n] = dD;
}

// ---------- partA: chunk LDS bucket sort, 4-B records, wave-scan ----------
__global__ void __launch_bounds__(512)
partA(MP4 a4, int mp_base, int NB) {
  const MP a = a4.m[mp_base + blockIdx.y];
  int k = blockIdx.x;
  if (k >= a.nchunks) return;
  __shared__ unsigned buf[CHUNK];       // 32 KB
  __shared__ int cnt[MAXNB];
  __shared__ int cur[MAXNB];
  __shared__ int off[MAXNB];
  __shared__ int posA[MAXNB];
  int t = threadIdx.x;
  int E = a.E;
  int base = k * CHUNK;
  int len = E - base; if (len > CHUNK) len = CHUNK;
  if (t < MAXNB) cnt[t] = 0;
  __syncthreads();                                          // B1
  // read (r,c) once, stash in registers; histogram
  int rr[16], cc[16];
  if (len == CHUNK && ((E & 3) == 0)) {
    const int4* eir = (const int4*)(a.ei + base);
    const int4* eic = (const int4*)(a.ei + E + base);
#pragma unroll
    for (int j = 0; j < 4; ++j) {
      int4 r4 = eir[j * 512 + t];
      int4 c4 = eic[j * 512 + t];
      rr[j * 4 + 0] = r4.x; cc[j * 4 + 0] = c4.x;
      rr[j * 4 + 1] = r4.y; cc[j * 4 + 1] = c4.y;
      rr[j * 4 + 2] = r4.z; cc[j * 4 + 2] = c4.z;
      rr[j * 4 + 3] = r4.w; cc[j * 4 + 3] = c4.w;
    }
  } else {
#pragma unroll
    for (int j = 0; j < 16; ++j) {
      int idx = j * 512 + t;
      rr[j] = -1;
      if (idx < len) { rr[j] = a.ei[base + idx]; cc[j] = a.ei[E + base + idx]; }
    }
  }
#pragma unroll
  for (int j = 0; j < 16; ++j)
    if (rr[j] >= 0) atomicAdd(&cnt[cc[j] >> NPB_SHIFT], 1);
  __syncthreads();                                          // B2
  // single-wave shfl scan over 256 buckets (4/lane) + global reservation
  if (t < 64) {
    int b0 = t * 4;
    int c0 = cnt[b0], c1 = cnt[b0 + 1], c2 = cnt[b0 + 2], c3 = cnt[b0 + 3];
    int s = c0 + c1 + c2 + c3;
    int inc = s;
#pragma unroll
    for (int d = 1; d < 64; d <<= 1) {
      int v = __shfl_up(inc, d, 64);
      if (t >= d) inc += v;
    }
    int run = inc - s;
    off[b0] = run;          cur[b0] = run;
    off[b0 + 1] = run + c0; cur[b0 + 1] = run + c0;
    off[b0 + 2] = run + c0 + c1; cur[b0 + 2] = run + c0 + c1;
    off[b0 + 3] = run + c0 + c1 + c2; cur[b0 + 3] = run + c0 + c1 + c2;
    posA[b0]     = c0 ? atomicAdd(&a.gcur[b0], c0) : 0;
    posA[b0 + 1] = c1 ? atomicAdd(&a.gcur[b0 + 1], c1) : 0;
    posA[b0 + 2] = c2 ? atomicAdd(&a.gcur[b0 + 2], c2) : 0;
    posA[b0 + 3] = c3 ? atomicAdd(&a.gcur[b0 + 3], c3) : 0;
  }
  __syncthreads();                                          // B3
  // placement: 4-B record (lc << 18) | r
#pragma unroll
  for (int j = 0; j < 16; ++j) {
    if (rr[j] >= 0) {
      int bb = cc[j] >> NPB_SHIFT;
      int p = atomicAdd(&cur[bb], 1);
      buf[p] = ((unsigned)(cc[j] & (NPB - 1)) << RSH) | (unsigned)rr[j];
    }
  }
  __syncthreads();                                          // B4
  // flush: wave per bucket segment -> contiguous nontemporal burst
  int wv = t >> 6, ln = t & 63;
  for (int s = wv; s < NB; s += 8) {
    int cn = cnt[s];
    if (cn == 0) continue;
    int c0 = off[s];
    int gb = posA[s];
    int lim = (s + 1) * a.rcap;
    int mx = lim - gb; if (mx < 0) mx = 0;
    if (cn > mx) cn = mx;
    for (int j = ln; j < cn; j += 64)
      __builtin_nontemporal_store(buf[c0 + j], &a.sorted[(size_t)gb + j]);
  }
}

// ---------- partB: LDS counting sort -> 4-deep batched walk, ONE gather/record ----------
// Packed row {h fp16, as fp32} is 32B-aligned -> the two loads hit the SAME
// cache line (miss-merged). Record streams stay nontemporal (protect L2 for pk).
__global__ void __launch_bounds__(1024)
partB(MP4 a4, int mp_base, int NB, int N, int fused) {
  int mp, b;
  if (fused) {
    int blk = blockIdx.x;
    int xcd = blk & 7;
    mp = xcd >> 1;
    b = ((blk >> 3) << 1) + (xcd & 1);
    if (b >= NB) return;
  } else {
    mp = mp_base;
    b = blockIdx.x;
  }
  const MP a = a4.m[mp];
  __shared__ unsigned key2[SUBCH];     // 32 KB
  __shared__ int cnt2[NPB];
  __shared__ int o2[NPB];
  __shared__ int cur2[NPB];
  int t = threadIdx.x;
  int s0i = b * a.rcap;
  int cnt = a.gcur[b] - s0i;
  if (cnt < 0) cnt = 0;
  if (cnt > a.rcap) cnt = a.rcap;
  const unsigned* run = a.sorted + (size_t)s0i;
  int basen = b << NPB_SHIFT;
  int n0 = basen + t;
  float ad0 = (n0 < N) ? a.ad[n0] : 0.f;
  const float* pk = a.pk;

  float acc0[HH];
#pragma unroll
  for (int f = 0; f < HH; ++f) acc0[f] = 0.f;
  float dn0 = 0.f;

  for (int c0 = 0; c0 < cnt; c0 += SUBCH) {
    int m = cnt - c0; if (m > SUBCH) m = SUBCH;
    cnt2[t] = 0;
    __syncthreads();                                        // B1
    // pass 1: histogram (nontemporal stream)
    for (int idx = t; idx < m; idx += 1024) {
      unsigned v = __builtin_nontemporal_load(run + c0 + idx);
      atomicAdd(&cnt2[v >> RSH], 1);
    }
    __syncthreads();                                        // B2
    // single-wave shfl scan over 1024 fine buckets (16/lane)
    if (t < 64) {
      int c[16];
      int s = 0;
#pragma unroll
      for (int j = 0; j < 16; ++j) { c[j] = cnt2[t * 16 + j]; s += c[j]; }
      int inc = s;
#pragma unroll
      for (int d = 1; d < 64; d <<= 1) {
        int v = __shfl_up(inc, d, 64);
        if (t >= d) inc += v;
      }
      int run2 = inc - s;
#pragma unroll
      for (int j = 0; j < 16; ++j) {
        o2[t * 16 + j] = run2;
        cur2[t * 16 + j] = run2;
        run2 += c[j];
      }
    }
    __syncthreads();                                        // B3
    // pass 2: placement
    for (int idx = t; idx < m; idx += 1024) {
      unsigned v = __builtin_nontemporal_load(run + c0 + idx);
      int p = atomicAdd(&cur2[v >> RSH], 1);
      key2[p] = v;
    }
    __syncthreads();                                        // B4
    // walk: 4-deep batched; ONE packed-row gather per record
    int j = o2[t], e = cur2[t];
    while (j < e) {
      int cn = e - j; if (cn > 4) cn = 4;
      int r_[4];
      float av[4];
      uint4 hv[4];
#pragma unroll
      for (int u = 0; u < 4; ++u) r_[u] = (u < cn) ? (int)(key2[j + u] & RMASK) : -1;
#pragma unroll
      for (int u = 0; u < 4; ++u) {
        if (r_[u] >= 0) {
          const float* rp = pk + (size_t)r_[u] * 8;
          hv[u] = *(const uint4*)rp;   // h[8] fp16, 16B
          av[u] = rp[4];               // as fp32, same 32B row -> same line
        }
      }
#pragma unroll
      for (int u = 0; u < 4; ++u) {
        if (r_[u] >= 0) {
          float w = __expf(lrelu(av[u] + ad0));
          dn0 += w;
          union { uint4 q; __half h[8]; } H; H.q = hv[u];
#pragma unroll
          for (int f = 0; f < HH; ++f) acc0[f] += w * __half2float(H.h[f]);
        }
      }
      j += cn;
    }
    if (c0 + SUBCH < cnt) __syncthreads();                  // B5 (between passes)
  }
  // epilogue: plain stores (score/pred re-read these soon)
  if (n0 < N) {
    float4* po = (float4*)(a.out + (size_t)n0 * HH);
    po[0] = make_float4(acc0[0], acc0[1], acc0[2], acc0[3]);
    po[1] = make_float4(acc0[4], acc0[5], acc0[6], acc0[7]);
    a.den[n0] = dn0;
  }
}

// ---------- semantic attention score (both groups, wave-shuffle reduce) ----------
__global__ void __launch_bounds__(256)
score_kernel(SC2 sc, int N,
             const void* __restrict__ kW, const void* __restrict__ kb,
             const void* __restrict__ qv, const int* __restrict__ flag) {
  const SC S = sc.g[blockIdx.y];
  __shared__ float kWl[HH][HH];
  __shared__ float kbl[HH], ql[HH];
  __shared__ float r0[4], r1[4];
  int isf = flag[0];
  int t = threadIdx.x;
  if (t < HH * HH) kWl[t >> 3][t & 7] = ld(kW, t, isf);
  if (t < HH) { kbl[t] = ld(kb, t, isf); ql[t] = ld(qv, t, isf); }
  __syncthreads();
  int n = blockIdx.x * blockDim.x + t;
  float s0 = 0.f, s1 = 0.f;
  if (n < N) {
    const float* p0 = S.o0 + (size_t)n * HH;
    const float* p1 = S.o1 + (size_t)n * HH;
    float i0 = 1.f / (S.d0[n] + 1e-16f);
    float i1 = 1.f / (S.d1[n] + 1e-16f);
    float v0[HH], v1[HH];
#pragma unroll
    for (int j = 0; j < HH; ++j) { v0[j] = fmaxf(p0[j] * i0, 0.f); v1[j] = fmaxf(p1[j] * i1, 0.f); }
#pragma unroll
    for (int j = 0; j < HH; ++j) {
      float t0 = kbl[j], t1 = kbl[j];
#pragma unroll
      for (int i = 0; i < HH; ++i) { t0 += v0[i] * kWl[i][j]; t1 += v1[i] * kWl[i][j]; }
      s0 += tanhf_fast(t0) * ql[j];
      s1 += tanhf_fast(t1) * ql[j];
    }
  }
#pragma unroll
  for (int d = 32; d > 0; d >>= 1) {
    s0 += __shfl_down(s0, d, 64);
    s1 += __shfl_down(s1, d, 64);
  }
  int wv = t >> 6, ln = t & 63;
  if (ln == 0) { r0[wv] = s0; r1[wv] = s1; }
  __syncthreads();
  if (t == 0) {
    atomicAdd(&S.score[0], r0[0] + r0[1] + r0[2] + r0[3]);
    atomicAdd(&S.score[1], r1[0] + r1[1] + r1[2] + r1[3]);
  }
}

// ---------- softmax over 2 metapaths + prediction head (both groups) ----------
__global__ void __launch_bounds__(256)
pred_kernel(PR2 pr, int N, const int* __restrict__ flag) {
  const PR P = pr.g[blockIdx.y];
  int isf = flag[0];
  int n = blockIdx.x * blockDim.x + threadIdx.x;
  if (n >= N) return;
  float s0 = P.score[0] / (float)N, s1 = P.score[1] / (float)N;
  float mx = fmaxf(s0, s1);
  float e0 = __expf(s0 - mx), e1 = __expf(s1 - mx);
  float inv = 1.f / (e0 + e1);
  float a0 = e0 * inv, a1 = e1 * inv;
  const float* p0 = P.o0 + (size_t)n * HH;
  const float* p1 = P.o1 + (size_t)n * HH;
  float i0 = 1.f / (P.d0[n] + 1e-16f);
  float i1 = 1.f / (P.d1[n] + 1e-16f);
  float acc = ld(P.linb, 0, isf);
#pragma unroll
  for (int j = 0; j < HH; ++j) {
    float z = a0 * fmaxf(p0[j] * i0, 0.f) + a1 * fmaxf(p1[j] * i1, 0.f);
    acc += z * ld(P.linW, j, isf);
  }
  P.outp[n] = 1.f / (1.f + __expf(-acc));
}

// ---------- launch ----------
extern "C" void kernel_launch(void* const* d_in, const int* in_sizes, int n_in,
                              void* d_out, int out_size, void* d_ws, size_t ws_size,
                              hipStream_t stream) {
  const int N = in_sizes[0] / FIN;

  const void* x_ind = d_in[0];
  const void* x_org = d_in[1];
  const void* x_ext = d_in[2];
  const int* ei_io = (const int*)d_in[3];  int E_io = in_sizes[3] / 2;  // ind->org
  const int* ei_oi = (const int*)d_in[4];  int E_oi = in_sizes[4] / 2;  // org->ind
  const int* ei_ei = (const int*)d_in[5];  int E_ei = in_sizes[5] / 2;  // ext->ind
  const int* ei_eo = (const int*)d_in[6];  int E_eo = in_sizes[6] / 2;  // ext->org
  const void* W_ind = d_in[7];
  const void* b_ind = d_in[8];
  const void* W_org = d_in[9];
  const void* b_org = d_in[10];
  const void* W_ext = d_in[11];
  const void* b_ext = d_in[12];
  const void* att_src_io = d_in[13];
  const void* att_dst_io = d_in[14];
  const void* att_src_oi = d_in[15];
  const void* att_dst_oi = d_in[16];
  const void* att_src_ei = d_in[17];
  const void* att_dst_ei = d_in[18];
  const void* att_src_eo = d_in[19];
  const void* att_dst_eo = d_in[20];
  const void* k_W = d_in[21];
  const void* k_b = d_in[22];
  const void* qv  = d_in[23];
  const void* lin_ind_W = d_in[24];
  const void* lin_ind_b = d_in[25];
  const void* lin_org_W = d_in[26];
  const void* lin_org_b = d_in[27];

  float* out_f = (float*)d_out;

  int E_max = E_io;
  if (E_oi > E_max) E_max = E_oi;
  if (E_ei > E_max) E_max = E_ei;
  if (E_eo > E_max) E_max = E_eo;

  const int NB = (N + NPB - 1) >> NPB_SHIFT;
  const int nchunks_max = (E_max + CHUNK - 1) / CHUNK;
  const int rcap = (int)(((long long)E_max / NB) * 115 / 100) + 128;

  // workspace layout (floats); pk arrays FIRST for 32B row alignment
  float* ws = (float*)d_ws;
  size_t off = 0;
  float* pk0 = ws + off; off += (size_t)N * 8;   // mp0: h_org + as_oi
  float* pk1 = ws + off; off += (size_t)N * 8;   // mp1: h_ext + as_ei
  float* pk2 = ws + off; off += (size_t)N * 8;   // mp2: h_ind + as_io
  float* pk3 = ws + off; off += (size_t)N * 8;   // mp3: h_ext + as_eo
  float* ad_oi = ws + off; off += N;
  float* ad_ei = ws + off; off += N;
  float* ad_io = ws + off; off += N;
  float* ad_eo = ws + off; off += N;
  float* den_all = ws + off; off += (size_t)4 * N;
  float* out_all = ws + off; off += (size_t)4 * N * HH;
  float* score_all = ws + off; off += 4;
  int* flag = (int*)(ws + off); off += 1;
  off = (off + 1) & ~(size_t)1;
  int* gcur0 = (int*)(ws + off); off += 4 * 256;

  size_t sort_f = (size_t)NB * rcap;   // u32 per record, in floats
  bool big = (off + 4 * sort_f) * sizeof(float) <= ws_size;
  int slots = big ? 4 : 1;
  unsigned* sorted0 = (unsigned*)(ws + off); off += (size_t)slots * sort_f;

  const int BS = 256;
  const int nb_node = (N + BS - 1) / BS;

  setup_kernel<<<1, 1024, 0, stream>>>((const unsigned short*)x_ind, flag, score_all, gcur0, rcap);

  // fused projections (3 node types in one grid)
  PJ3 pj;
  pj.p[0] = PJ{x_ind, W_ind, b_ind,
               att_src_io, pk2, nullptr, nullptr,
               att_dst_oi, ad_oi, att_dst_ei, ad_ei};
  pj.p[1] = PJ{x_org, W_org, b_org,
               att_src_oi, pk0, nullptr, nullptr,
               att_dst_io, ad_io, att_dst_eo, ad_eo};
  pj.p[2] = PJ{x_ext, W_ext, b_ext,
               att_src_ei, pk1, att_src_eo, pk3,
               nullptr, nullptr, nullptr, nullptr};
  proj_kernel<<<dim3(nb_node, 3), BS, 0, stream>>>(pj, N, flag);

  // metapath table: mp0 org->ind, mp1 ext->ind, mp2 ind->org, mp3 ext->org
  const int* eis[4]     = {ei_oi, ei_ei, ei_io, ei_eo};
  int        Es[4]      = {E_oi, E_ei, E_io, E_eo};
  const float* ads[4]   = {ad_oi, ad_ei, ad_io, ad_eo};
  const float* pks[4]   = {pk0, pk1, pk2, pk3};

  MP4 a4;
  for (int mp = 0; mp < 4; ++mp) {
    MP& a = a4.m[mp];
    a.ei = eis[mp];
    a.ad = ads[mp];
    a.pk = pks[mp];
    a.den = den_all + (size_t)mp * N;
    a.out = out_all + (size_t)mp * N * HH;
    a.sorted = sorted0 + (size_t)(big ? mp : 0) * sort_f;
    a.gcur = gcur0 + mp * 256;
    a.E = Es[mp];
    a.nchunks = (Es[mp] + CHUNK - 1) / CHUNK;
    a.rcap = rcap;
  }

  if (big) {
    partA<<<dim3(nchunks_max, 4), 512, 0, stream>>>(a4, 0, NB);
    int nblkB = 8 * ((NB + 1) >> 1);
    partB<<<dim3(nblkB, 1), 1024, 0, stream>>>(a4, 0, NB, N, 1);
  } else {
    for (int mp = 0; mp < 4; ++mp) {
      partA<<<dim3(a4.m[mp].nchunks, 1), 512, 0, stream>>>(a4, mp, NB);
      partB<<<dim3(NB, 1), 1024, 0, stream>>>(a4, mp, NB, N, 0);
    }
  }

  float* o_ind0 = out_all + (size_t)0 * N * HH;
  float* o_ind1 = out_all + (size_t)1 * N * HH;
  float* o_org0 = out_all + (size_t)2 * N * HH;
  float* o_org1 = out_all + (size_t)3 * N * HH;
  float* d_ind0 = den_all + (size_t)0 * N;
  float* d_ind1 = den_all + (size_t)1 * N;
  float* d_org0 = den_all + (size_t)2 * N;
  float* d_org1 = den_all + (size_t)3 * N;

  SC2 sc;
  sc.g[0] = SC{o_ind0, d_ind0, o_ind1, d_ind1, score_all};
  sc.g[1] = SC{o_org0, d_org0, o_org1, d_org1, score_all + 2};
  score_kernel<<<dim3(nb_node, 2), BS, 0, stream>>>(sc, N, k_W, k_b, qv, flag);

  PR2 pr;
  pr.g[0] = PR{o_ind0, d_ind0, o_ind1, d_ind1, score_all, lin_ind_W, lin_ind_b, out_f};
  pr.g[1] = PR{o_org0, d_org0, o_org1, d_org1, score_all + 2, lin_org_W, lin_org_b, out_f + N};
  pred_kernel<<<dim3(nb_node, 2), BS, 0, stream>>>(pr, N, flag);
}

// Round 14
// 531.491 us; speedup vs baseline: 1.1287x; 1.1287x over previous
//
#include <hip/hip_runtime.h>
#include <hip/hip_fp16.h>

#define HH 8
#define FIN 64
#define CHUNK 8192       // edges per partA block
#define NPB 1024         // dst nodes per bucket
#define NPB_SHIFT 10
#define MAXNB 256        // max buckets (N <= 262144; also r must fit 18 bits)
#define SUBCH 4096       // records per partB sub-chunk
#define RSH 18           // record: (local_c << RSH) | r
#define RMASK 0x3FFFFu

// ---------- helpers ----------
__device__ __forceinline__ float b2f(unsigned short u) {
  union { unsigned int i; float f; } x;
  x.i = ((unsigned int)u) << 16;
  return x.f;
}

__device__ __forceinline__ float lrelu(float x) { return x > 0.f ? x : 0.2f * x; }

__device__ __forceinline__ float ld(const void* p, int i, int isf) {
  return isf ? ((const float*)p)[i] : b2f(((const unsigned short*)p)[i]);
}

// fast tanh via __expf (clamped; |err| ~1e-7 in the used range)
__device__ __forceinline__ float tanhf_fast(float x) {
  float xc = fminf(fmaxf(x, -15.f), 15.f);
  float e = __expf(2.f * xc);
  return 1.f - 2.f / (e + 1.f);
}

// per-metapath argument bundle
struct MP {
  const int* ei;
  const float* as;
  const float* ad;
  const __half* hs;     // fp16 projected features (3.2 MB, L2-resident)
  float* den;
  float* out;
  unsigned* sorted;     // 4-B records, bucket b at [b*rcap, ...)
  int* gcur;            // per-bucket allocation cursors (256 ints)
  int E;
  int nchunks;
  int rcap;
};
struct MP4 { MP m[4]; };

// projection bundle (3 node types in one launch)
struct PJ {
  const void* x; const void* W; const void* b; __half* h16;
  const void* a0; float* s0;
  const void* a1; float* s1;
  const void* a2; float* s2;
};
struct PJ3 { PJ p[3]; };

struct PR { const float *o0, *d0, *o1, *d1; const float* score;
            const void* linW; const void* linb; float* outp; };
struct PR2 { PR g[2]; };

// ---------- setup: dtype detect + zero score + init cursors (one launch) ----------
__global__ void __launch_bounds__(1024)
setup_kernel(const unsigned short* __restrict__ x, int* __restrict__ flag,
             float* __restrict__ score_all, int* __restrict__ gcur, int rcap) {
  __shared__ int tot;
  int t = threadIdx.x;
  gcur[t] = (t & 255) * rcap;
  if (t < 4) score_all[t] = 0.f;
  if (t == 0) tot = 0;
  __syncthreads();
  int cnt = 0;
  for (int i = t; i < 2048; i += 1024) {
    int e = (x[i] >> 7) & 0xFF;
    if (e >= 0x90) cnt++;
  }
  if (cnt) atomicAdd(&tot, cnt);
  __syncthreads();
  if (t == 0) flag[0] = (tot >= 8) ? 1 : 0;
}

// ---------- projection: h16 = fp16(x @ W + b), plus up to 3 attention dots ----------
__global__ void __launch_bounds__(256)
proj_kernel(PJ3 pj, int N, const int* __restrict__ flag) {
  const PJ P = pj.p[blockIdx.y];
  __shared__ float Wl[FIN][HH];
  __shared__ float bl[HH];
  __shared__ float al[3][HH];
  int isf = flag[0];
  int t = threadIdx.x;
  for (int i = t; i < FIN * HH; i += blockDim.x) Wl[i >> 3][i & 7] = ld(P.W, i, isf);
  if (t < HH) {
    bl[t] = ld(P.b, t, isf);
    al[0][t] = P.a0 ? ld(P.a0, t, isf) : 0.f;
    al[1][t] = P.a1 ? ld(P.a1, t, isf) : 0.f;
    al[2][t] = P.a2 ? ld(P.a2, t, isf) : 0.f;
  }
  __syncthreads();
  int n = blockIdx.x * blockDim.x + t;
  if (n >= N) return;
  float acc[HH];
#pragma unroll
  for (int j = 0; j < HH; ++j) acc[j] = bl[j];
  if (isf) {
    const float4* xr = (const float4*)((const float*)P.x + (size_t)n * FIN);
#pragma unroll
    for (int v = 0; v < FIN / 4; ++v) {
      float4 p = xr[v];
      float f4[4] = {p.x, p.y, p.z, p.w};
#pragma unroll
      for (int k = 0; k < 4; ++k) {
        int f = v * 4 + k;
#pragma unroll
        for (int j = 0; j < HH; ++j) acc[j] += f4[k] * Wl[f][j];
      }
    }
  } else {
    const uint4* xr = (const uint4*)((const unsigned short*)P.x + (size_t)n * FIN);
#pragma unroll
    for (int v = 0; v < FIN / 8; ++v) {
      uint4 p = xr[v];
      unsigned int w[4] = {p.x, p.y, p.z, p.w};
#pragma unroll
      for (int k = 0; k < 4; ++k) {
        float f0 = __uint_as_float(w[k] << 16);
        float f1 = __uint_as_float(w[k] & 0xFFFF0000u);
        int f = v * 8 + k * 2;
#pragma unroll
        for (int j = 0; j < HH; ++j) acc[j] += f0 * Wl[f][j];
#pragma unroll
        for (int j = 0; j < HH; ++j) acc[j] += f1 * Wl[f + 1][j];
      }
    }
  }
  union { __half h[8]; uint4 u; } pk;
#pragma unroll
  for (int j = 0; j < HH; ++j) pk.h[j] = __float2half(acc[j]);
  *(uint4*)(P.h16 + (size_t)n * HH) = pk.u;
  float d0 = 0.f, d1 = 0.f, d2 = 0.f;
#pragma unroll
  for (int j = 0; j < HH; ++j) {
    d0 += acc[j] * al[0][j];
    d1 += acc[j] * al[1][j];
    d2 += acc[j] * al[2][j];
  }
  if (P.s0) P.s0[n] = d0;
  if (P.s1) P.s1[n] = d1;
  if (P.s2) P.s2[n] = d2;
}

// ---------- partA: chunk LDS bucket sort, 4-B records, wave-scan ----------
__global__ void __launch_bounds__(512)
partA(MP4 a4, int mp_base, int NB) {
  const MP a = a4.m[mp_base + blockIdx.y];
  int k = blockIdx.x;
  if (k >= a.nchunks) return;
  __shared__ unsigned buf[CHUNK];       // 32 KB
  __shared__ int cnt[MAXNB];
  __shared__ int cur[MAXNB];
  __shared__ int off[MAXNB];
  __shared__ int posA[MAXNB];
  int t = threadIdx.x;
  int E = a.E;
  int base = k * CHUNK;
  int len = E - base; if (len > CHUNK) len = CHUNK;
  if (t < MAXNB) cnt[t] = 0;
  __syncthreads();                                          // B1
  // read (r,c) once, stash in registers; histogram
  int rr[16], cc[16];
  if (len == CHUNK && ((E & 3) == 0)) {
    const int4* eir = (const int4*)(a.ei + base);
    const int4* eic = (const int4*)(a.ei + E + base);
#pragma unroll
    for (int j = 0; j < 4; ++j) {
      int4 r4 = eir[j * 512 + t];
      int4 c4 = eic[j * 512 + t];
      rr[j * 4 + 0] = r4.x; cc[j * 4 + 0] = c4.x;
      rr[j * 4 + 1] = r4.y; cc[j * 4 + 1] = c4.y;
      rr[j * 4 + 2] = r4.z; cc[j * 4 + 2] = c4.z;
      rr[j * 4 + 3] = r4.w; cc[j * 4 + 3] = c4.w;
    }
  } else {
#pragma unroll
    for (int j = 0; j < 16; ++j) {
      int idx = j * 512 + t;
      rr[j] = -1;
      if (idx < len) { rr[j] = a.ei[base + idx]; cc[j] = a.ei[E + base + idx]; }
    }
  }
#pragma unroll
  for (int j = 0; j < 16; ++j)
    if (rr[j] >= 0) atomicAdd(&cnt[cc[j] >> NPB_SHIFT], 1);
  __syncthreads();                                          // B2
  // single-wave shfl scan over 256 buckets (4/lane) + global reservation
  if (t < 64) {
    int b0 = t * 4;
    int c0 = cnt[b0], c1 = cnt[b0 + 1], c2 = cnt[b0 + 2], c3 = cnt[b0 + 3];
    int s = c0 + c1 + c2 + c3;
    int inc = s;
#pragma unroll
    for (int d = 1; d < 64; d <<= 1) {
      int v = __shfl_up(inc, d, 64);
      if (t >= d) inc += v;
    }
    int run = inc - s;
    off[b0] = run;          cur[b0] = run;
    off[b0 + 1] = run + c0; cur[b0 + 1] = run + c0;
    off[b0 + 2] = run + c0 + c1; cur[b0 + 2] = run + c0 + c1;
    off[b0 + 3] = run + c0 + c1 + c2; cur[b0 + 3] = run + c0 + c1 + c2;
    posA[b0]     = c0 ? atomicAdd(&a.gcur[b0], c0) : 0;
    posA[b0 + 1] = c1 ? atomicAdd(&a.gcur[b0 + 1], c1) : 0;
    posA[b0 + 2] = c2 ? atomicAdd(&a.gcur[b0 + 2], c2) : 0;
    posA[b0 + 3] = c3 ? atomicAdd(&a.gcur[b0 + 3], c3) : 0;
  }
  __syncthreads();                                          // B3
  // placement: 4-B record (lc << 18) | r
#pragma unroll
  for (int j = 0; j < 16; ++j) {
    if (rr[j] >= 0) {
      int bb = cc[j] >> NPB_SHIFT;
      int p = atomicAdd(&cur[bb], 1);
      buf[p] = ((unsigned)(cc[j] & (NPB - 1)) << RSH) | (unsigned)rr[j];
    }
  }
  __syncthreads();                                          // B4
  // flush: wave per bucket segment -> contiguous nontemporal burst
  int wv = t >> 6, ln = t & 63;
  for (int s = wv; s < NB; s += 8) {
    int cn = cnt[s];
    if (cn == 0) continue;
    int c0 = off[s];
    int gb = posA[s];
    int lim = (s + 1) * a.rcap;
    int mx = lim - gb; if (mx < 0) mx = 0;
    if (cn > mx) cn = mx;
    for (int j = ln; j < cn; j += 64)
      __builtin_nontemporal_store(buf[c0 + j], &a.sorted[(size_t)gb + j]);
  }
}

// ---------- partB: r7 structure + fused semantic-score epilogue ----------
// 512 thr, dual-segment walk (nodes t and t+512), kk[8] register preload
// (records read once), exp recomputed from as/ad. After accumulation, each
// block computes its partial semantic score IN REGISTERS and atomicAdds once.
__global__ void __launch_bounds__(512)
partB(MP4 a4, int mp_base, int NB, int N, int fused,
      const void* __restrict__ kW, const void* __restrict__ kb,
      const void* __restrict__ qv, float* __restrict__ score_all,
      const int* __restrict__ flag) {
  int mp, b;
  if (fused) {
    int blk = blockIdx.x;
    int xcd = blk & 7;
    mp = xcd >> 1;
    b = ((blk >> 3) << 1) + (xcd & 1);
    if (b >= NB) return;
  } else {
    mp = mp_base;
    b = blockIdx.x;
  }
  const MP a = a4.m[mp];
  __shared__ unsigned key2[SUBCH];     // 16 KB
  __shared__ int cnt2[NPB];
  __shared__ int o2[NPB];
  __shared__ int cur2[NPB];
  __shared__ float kWl[HH * HH];
  __shared__ float kbl[HH], ql[HH];
  __shared__ float red[8];
  int t = threadIdx.x;
  int isf = flag[0];
  if (t < HH * HH) kWl[t] = ld(kW, t, isf);
  if (t < HH) { kbl[t] = ld(kb, t, isf); ql[t] = ld(qv, t, isf); }
  int s0i = b * a.rcap;
  int cnt = a.gcur[b] - s0i;
  if (cnt < 0) cnt = 0;
  if (cnt > a.rcap) cnt = a.rcap;
  const unsigned* run = a.sorted + (size_t)s0i;
  int basen = b << NPB_SHIFT;
  int n0 = basen + t, n1 = basen + t + 512;
  float ad0 = (n0 < N) ? a.ad[n0] : 0.f;
  float ad1 = (n1 < N) ? a.ad[n1] : 0.f;
  const float* asp = a.as;
  const __half* hs = a.hs;

  float acc0[HH], acc1[HH];
#pragma unroll
  for (int f = 0; f < HH; ++f) { acc0[f] = 0.f; acc1[f] = 0.f; }
  float dn0 = 0.f, dn1 = 0.f;

  // preload first sub-chunk into registers (records read once from global)
  unsigned kk[8];
  int vld[8];
  {
    int m0 = cnt < SUBCH ? cnt : SUBCH;
#pragma unroll
    for (int u = 0; u < 8; ++u) {
      int idx = u * 512 + t;
      vld[u] = idx < m0;
      if (vld[u]) kk[u] = __builtin_nontemporal_load(run + idx);
    }
  }

  for (int c0 = 0; c0 < cnt; c0 += SUBCH) {
    cnt2[t] = 0; cnt2[t + 512] = 0;
    __syncthreads();                                        // B1
#pragma unroll
    for (int u = 0; u < 8; ++u)
      if (vld[u]) atomicAdd(&cnt2[kk[u] >> RSH], 1);
    __syncthreads();                                        // B2
    // single-wave shfl scan over 1024 fine buckets (16/lane)
    if (t < 64) {
      int c[16];
      int s = 0;
#pragma unroll
      for (int j = 0; j < 16; ++j) { c[j] = cnt2[t * 16 + j]; s += c[j]; }
      int inc = s;
#pragma unroll
      for (int d = 1; d < 64; d <<= 1) {
        int v = __shfl_up(inc, d, 64);
        if (t >= d) inc += v;
      }
      int run2 = inc - s;
#pragma unroll
      for (int j = 0; j < 16; ++j) {
        o2[t * 16 + j] = run2;
        cur2[t * 16 + j] = run2;
        run2 += c[j];
      }
    }
    __syncthreads();                                        // B3
    // placement (int atomics, random 4-B LDS writes)
#pragma unroll
    for (int u = 0; u < 8; ++u) {
      if (vld[u]) {
        int p = atomicAdd(&cur2[kk[u] >> RSH], 1);
        key2[p] = kk[u];
      }
    }
    __syncthreads();                                        // B4
    // prefetch next sub-chunk (overlaps walk)
    int cn0 = c0 + SUBCH;
    unsigned nk[8];
    int nv[8];
    {
      int mn = cnt - cn0; if (mn > SUBCH) mn = SUBCH;
#pragma unroll
      for (int u = 0; u < 8; ++u) {
        int idx = u * 512 + t;
        nv[u] = (cn0 < cnt) && (idx < mn);
        if (nv[u]) nk[u] = __builtin_nontemporal_load(run + (size_t)cn0 + idx);
      }
    }
    // dual-segment walk (two independent chains)
    int j0 = o2[t], e0 = cur2[t];
    int j1 = o2[t + 512], e1 = cur2[t + 512];
    while (j0 < e0 || j1 < e1) {
      if (j0 < e0) {
        unsigned v = key2[j0++];
        int r = (int)(v & RMASK);
        float w = __expf(lrelu(asp[r] + ad0));
        union { uint4 u; __half h[8]; } H;
        H.u = *(const uint4*)(hs + (size_t)r * HH);
        dn0 += w;
#pragma unroll
        for (int f = 0; f < HH; ++f) acc0[f] += w * __half2float(H.h[f]);
      }
      if (j1 < e1) {
        unsigned v = key2[j1++];
        int r = (int)(v & RMASK);
        float w = __expf(lrelu(asp[r] + ad1));
        union { uint4 u; __half h[8]; } H;
        H.u = *(const uint4*)(hs + (size_t)r * HH);
        dn1 += w;
#pragma unroll
        for (int f = 0; f < HH; ++f) acc1[f] += w * __half2float(H.h[f]);
      }
    }
    __syncthreads();                                        // B5
#pragma unroll
    for (int u = 0; u < 8; ++u) { vld[u] = nv[u]; kk[u] = nk[u]; }
  }
  // out/den stores (exclusive node ownership)
  if (n0 < N) {
    float4* po = (float4*)(a.out + (size_t)n0 * HH);
    po[0] = make_float4(acc0[0], acc0[1], acc0[2], acc0[3]);
    po[1] = make_float4(acc0[4], acc0[5], acc0[6], acc0[7]);
    a.den[n0] = dn0;
  }
  if (n1 < N) {
    float4* po = (float4*)(a.out + (size_t)n1 * HH);
    po[0] = make_float4(acc1[0], acc1[1], acc1[2], acc1[3]);
    po[1] = make_float4(acc1[4], acc1[5], acc1[6], acc1[7]);
    a.den[n1] = dn1;
  }
  // fused semantic-score partial: sum tanh(relu(o/den)@kW + kb) . q over owned nodes
  float sc = 0.f;
  if (n0 < N) {
    float inv = 1.f / (dn0 + 1e-16f);
    float v[HH];
#pragma unroll
    for (int j = 0; j < HH; ++j) v[j] = fmaxf(acc0[j] * inv, 0.f);
#pragma unroll
    for (int j = 0; j < HH; ++j) {
      float z = kbl[j];
#pragma unroll
      for (int i = 0; i < HH; ++i) z += v[i] * kWl[i * HH + j];
      sc += tanhf_fast(z) * ql[j];
    }
  }
  if (n1 < N) {
    float inv = 1.f / (dn1 + 1e-16f);
    float v[HH];
#pragma unroll
    for (int j = 0; j < HH; ++j) v[j] = fmaxf(acc1[j] * inv, 0.f);
#pragma unroll
    for (int j = 0; j < HH; ++j) {
      float z = kbl[j];
#pragma unroll
      for (int i = 0; i < HH; ++i) z += v[i] * kWl[i * HH + j];
      sc += tanhf_fast(z) * ql[j];
    }
  }
#pragma unroll
  for (int d = 32; d > 0; d >>= 1) sc += __shfl_down(sc, d, 64);
  int wv = t >> 6, ln = t & 63;
  if (ln == 0) red[wv] = sc;
  __syncthreads();
  if (t == 0) {
    float tt = 0.f;
#pragma unroll
    for (int i = 0; i < 8; ++i) tt += red[i];
    atomicAdd(&score_all[mp], tt);
  }
}

// ---------- softmax over 2 metapaths + prediction head (both groups) ----------
__global__ void __launch_bounds__(256)
pred_kernel(PR2 pr, int N, const int* __restrict__ flag) {
  const PR P = pr.g[blockIdx.y];
  int isf = flag[0];
  int n = blockIdx.x * blockDim.x + threadIdx.x;
  if (n >= N) return;
  float s0 = P.score[0] / (float)N, s1 = P.score[1] / (float)N;
  float mx = fmaxf(s0, s1);
  float e0 = __expf(s0 - mx), e1 = __expf(s1 - mx);
  float inv = 1.f / (e0 + e1);
  float a0 = e0 * inv, a1 = e1 * inv;
  const float* p0 = P.o0 + (size_t)n * HH;
  const float* p1 = P.o1 + (size_t)n * HH;
  float i0 = 1.f / (P.d0[n] + 1e-16f);
  float i1 = 1.f / (P.d1[n] + 1e-16f);
  float acc = ld(P.linb, 0, isf);
#pragma unroll
  for (int j = 0; j < HH; ++j) {
    float z = a0 * fmaxf(p0[j] * i0, 0.f) + a1 * fmaxf(p1[j] * i1, 0.f);
    acc += z * ld(P.linW, j, isf);
  }
  P.outp[n] = 1.f / (1.f + __expf(-acc));
}

// ---------- launch ----------
extern "C" void kernel_launch(void* const* d_in, const int* in_sizes, int n_in,
                              void* d_out, int out_size, void* d_ws, size_t ws_size,
                              hipStream_t stream) {
  const int N = in_sizes[0] / FIN;

  const void* x_ind = d_in[0];
  const void* x_org = d_in[1];
  const void* x_ext = d_in[2];
  const int* ei_io = (const int*)d_in[3];  int E_io = in_sizes[3] / 2;  // ind->org
  const int* ei_oi = (const int*)d_in[4];  int E_oi = in_sizes[4] / 2;  // org->ind
  const int* ei_ei = (const int*)d_in[5];  int E_ei = in_sizes[5] / 2;  // ext->ind
  const int* ei_eo = (const int*)d_in[6];  int E_eo = in_sizes[6] / 2;  // ext->org
  const void* W_ind = d_in[7];
  const void* b_ind = d_in[8];
  const void* W_org = d_in[9];
  const void* b_org = d_in[10];
  const void* W_ext = d_in[11];
  const void* b_ext = d_in[12];
  const void* att_src_io = d_in[13];
  const void* att_dst_io = d_in[14];
  const void* att_src_oi = d_in[15];
  const void* att_dst_oi = d_in[16];
  const void* att_src_ei = d_in[17];
  const void* att_dst_ei = d_in[18];
  const void* att_src_eo = d_in[19];
  const void* att_dst_eo = d_in[20];
  const void* k_W = d_in[21];
  const void* k_b = d_in[22];
  const void* qv  = d_in[23];
  const void* lin_ind_W = d_in[24];
  const void* lin_ind_b = d_in[25];
  const void* lin_org_W = d_in[26];
  const void* lin_org_b = d_in[27];

  float* out_f = (float*)d_out;

  int E_max = E_io;
  if (E_oi > E_max) E_max = E_oi;
  if (E_ei > E_max) E_max = E_ei;
  if (E_eo > E_max) E_max = E_eo;

  const int NB = (N + NPB - 1) >> NPB_SHIFT;
  const int nchunks_max = (E_max + CHUNK - 1) / CHUNK;
  const int rcap = (int)(((long long)E_max / NB) * 115 / 100) + 128;

  // workspace layout (floats)
  float* ws = (float*)d_ws;
  size_t off = 0;
  __half* h16_ind = (__half*)(ws + off); off += (size_t)N * HH / 2;
  __half* h16_org = (__half*)(ws + off); off += (size_t)N * HH / 2;
  __half* h16_ext = (__half*)(ws + off); off += (size_t)N * HH / 2;
  float* as_io = ws + off; off += N;
  float* ad_oi = ws + off; off += N;
  float* ad_ei = ws + off; off += N;
  float* as_oi = ws + off; off += N;
  float* ad_io = ws + off; off += N;
  float* ad_eo = ws + off; off += N;
  float* as_ei = ws + off; off += N;
  float* as_eo = ws + off; off += N;
  float* den_all = ws + off; off += (size_t)4 * N;
  float* out_all = ws + off; off += (size_t)4 * N * HH;
  float* score_all = ws + off; off += 4;
  int* flag = (int*)(ws + off); off += 1;
  off = (off + 1) & ~(size_t)1;
  int* gcur0 = (int*)(ws + off); off += 4 * 256;

  size_t sort_f = (size_t)NB * rcap;   // u32 per record, in floats
  bool big = (off + 4 * sort_f) * sizeof(float) <= ws_size;
  int slots = big ? 4 : 1;
  unsigned* sorted0 = (unsigned*)(ws + off); off += (size_t)slots * sort_f;

  const int BS = 256;
  const int nb_node = (N + BS - 1) / BS;

  setup_kernel<<<1, 1024, 0, stream>>>((const unsigned short*)x_ind, flag, score_all, gcur0, rcap);

  // fused projections (3 node types in one grid)
  PJ3 pj;
  pj.p[0] = PJ{x_ind, W_ind, b_ind, h16_ind, att_src_io, as_io, att_dst_oi, ad_oi, att_dst_ei, ad_ei};
  pj.p[1] = PJ{x_org, W_org, b_org, h16_org, att_src_oi, as_oi, att_dst_io, ad_io, att_dst_eo, ad_eo};
  pj.p[2] = PJ{x_ext, W_ext, b_ext, h16_ext, att_src_ei, as_ei, att_src_eo, as_eo, nullptr, nullptr};
  proj_kernel<<<dim3(nb_node, 3), BS, 0, stream>>>(pj, N, flag);

  // metapath table: mp0 org->ind, mp1 ext->ind, mp2 ind->org, mp3 ext->org
  const int* eis[4]       = {ei_oi, ei_ei, ei_io, ei_eo};
  int        Es[4]        = {E_oi, E_ei, E_io, E_eo};
  const float* ass[4]     = {as_oi, as_ei, as_io, as_eo};
  const float* ads[4]     = {ad_oi, ad_ei, ad_io, ad_eo};
  const __half* hsrcs[4]  = {h16_org, h16_ext, h16_ind, h16_ext};

  MP4 a4;
  for (int mp = 0; mp < 4; ++mp) {
    MP& a = a4.m[mp];
    a.ei = eis[mp];
    a.as = ass[mp];
    a.ad = ads[mp];
    a.hs = hsrcs[mp];
    a.den = den_all + (size_t)mp * N;
    a.out = out_all + (size_t)mp * N * HH;
    a.sorted = sorted0 + (size_t)(big ? mp : 0) * sort_f;
    a.gcur = gcur0 + mp * 256;
    a.E = Es[mp];
    a.nchunks = (Es[mp] + CHUNK - 1) / CHUNK;
    a.rcap = rcap;
  }

  if (big) {
    partA<<<dim3(nchunks_max, 4), 512, 0, stream>>>(a4, 0, NB);
    int nblkB = 8 * ((NB + 1) >> 1);
    partB<<<dim3(nblkB, 1), 512, 0, stream>>>(a4, 0, NB, N, 1, k_W, k_b, qv, score_all, flag);
  } else {
    for (int mp = 0; mp < 4; ++mp) {
      partA<<<dim3(a4.m[mp].nchunks, 1), 512, 0, stream>>>(a4, mp, NB);
      partB<<<dim3(NB, 1), 512, 0, stream>>>(a4, mp, NB, N, 0, k_W, k_b, qv, score_all, flag);
    }
  }

  float* o_ind0 = out_all + (size_t)0 * N * HH;
  float* o_ind1 = out_all + (size_t)1 * N * HH;
  float* o_org0 = out_all + (size_t)2 * N * HH;
  float* o_org1 = out_all + (size_t)3 * N * HH;
  float* d_ind0 = den_all + (size_t)0 * N;
  float* d_ind1 = den_all + (size_t)1 * N;
  float* d_org0 = den_all + (size_t)2 * N;
  float* d_org1 = den_all + (size_t)3 * N;

  PR2 pr;
  pr.g[0] = PR{o_ind0, d_ind0, o_ind1, d_ind1, score_all, lin_ind_W, lin_ind_b, out_f};
  pr.g[1] = PR{o_org0, d_org0, o_org1, d_org1, score_all + 2, lin_org_W, lin_org_b, out_f + N};
  pred_kernel<<<dim3(nb_node, 2), BS, 0, stream>>>(pr, N, flag);
}